// Round 3
// baseline (522.443 us; speedup 1.0000x reference)
//
#include <hip/hip_runtime.h>
#include <hip/hip_bf16.h>
#include <math.h>

// Problem constants
#define T_SEQ 4096
#define NEMB  2048
#define NH    16
#define NKV   4
#define HD    128
#define WIN   1024

typedef __attribute__((ext_vector_type(8))) __bf16 bf16x8;
typedef __attribute__((ext_vector_type(4))) float  f32x4;

__device__ __forceinline__ float wave_sum64(float v) {
#pragma unroll
  for (int off = 1; off < 64; off <<= 1) v += __shfl_xor(v, off, 64);
  return v;
}
__device__ __forceinline__ float wave_max64(float v) {
#pragma unroll
  for (int off = 1; off < 64; off <<= 1) v = fmaxf(v, __shfl_xor(v, off, 64));
  return v;
}

// ---- cast+split x: xsplit[4096][4096] = [x_hi | x_lo], 8 elems/thread ----
__global__ __launch_bounds__(256) void cast_x_split_kernel(const float* __restrict__ src,
                                                           __bf16* __restrict__ dst) {
  int i = blockIdx.x * 256 + threadIdx.x;   // 1M groups of 8
  int row = i >> 8, colg = i & 255;         // 256 groups per 2048-col row
  const f32x4* s4 = (const f32x4*)src;
  f32x4 a = s4[2 * i], b = s4[2 * i + 1];
  bf16x8 hi, lo;
#pragma unroll
  for (int j = 0; j < 4; ++j) {
    hi[j] = (__bf16)a[j]; lo[j] = (__bf16)(a[j] - (float)hi[j]);
    hi[j + 4] = (__bf16)b[j]; lo[j + 4] = (__bf16)(b[j] - (float)hi[j + 4]);
  }
  *(bf16x8*)(dst + (size_t)row * 4096 + colg * 8) = hi;
  *(bf16x8*)(dst + (size_t)row * 4096 + 2048 + colg * 8) = lo;
}

// ------- transpose-cast: src f32 [K=2048][N] -> dst bf16 [N][2048] ------------
__global__ __launch_bounds__(64) void transpose_cast_kernel(const float* __restrict__ src,
                                                            __bf16* __restrict__ dst,
                                                            int K, int N) {
  int kc = blockIdx.x * 8;
  int n  = blockIdx.y * 64 + threadIdx.x;
  bf16x8 o;
#pragma unroll
  for (int j = 0; j < 8; ++j) o[j] = (__bf16)src[(size_t)(kc + j) * N + n];
  *(bf16x8*)(dst + (size_t)n * K + kc) = o;
}

// ---- transpose-split-cast: src f32 [2048][N] -> dst[n][0:2048]=hi,
// ---- dst[n][2048:4096]=hi, dst[n][4096:6144]=lo  (row stride ld=6144) ----
__global__ __launch_bounds__(64) void transpose_split_kernel(const float* __restrict__ src,
                                                             __bf16* __restrict__ dst,
                                                             int N) {
  int kc = blockIdx.x * 8;
  int n  = blockIdx.y * 64 + threadIdx.x;
  bf16x8 hi, lo;
#pragma unroll
  for (int j = 0; j < 8; ++j) {
    float v = src[(size_t)(kc + j) * N + n];
    hi[j] = (__bf16)v; lo[j] = (__bf16)(v - (float)hi[j]);
  }
  *(bf16x8*)(dst + (size_t)n * 6144 + kc) = hi;
  *(bf16x8*)(dst + (size_t)n * 6144 + 2048 + kc) = hi;
  *(bf16x8*)(dst + (size_t)n * 6144 + 4096 + kc) = lo;
}

// ---------------- bf16 MFMA GEMM: C[M,N] = A[M,K] * BT[N,K]^T ----------------
// 128x128 tile, BK=64, 4 waves (2x2), 4x4 16x16 frags/wave, XOR-swizzled LDS.
// A col index wraps at `awrap` (for the 3-term split GEMM: cols [4096,6144)
// re-read x_hi). lda/ldb are row strides of A/BT.
template <bool OUT_BF16>
__global__ __launch_bounds__(256) void gemm_kernel(const __bf16* __restrict__ A,
                                                   const __bf16* __restrict__ BT,
                                                   void* __restrict__ Cout,
                                                   int M, int N, int K,
                                                   int lda, int ldb, int awrap) {
  __shared__ bf16x8 As[1024];  // [row 0..127][cg 0..7], slot = row*8 + (cg ^ (row&7))
  __shared__ bf16x8 Bs[1024];
  const int tid = threadIdx.x;
  const int lane = tid & 63, w = tid >> 6;
  const int wr = w >> 1, wc = w & 1;
  const int g = lane >> 4, c = lane & 15;
  const int m0 = blockIdx.y * 128, n0 = blockIdx.x * 128;
  const int rs = tid >> 3, cs = tid & 7;
  f32x4 acc[4][4] = {};
  for (int k0 = 0; k0 < K; k0 += 64) {
    int ka = k0 + cs * 8;
    int kaw = (ka >= awrap) ? ka - awrap : ka;
    __syncthreads();
#pragma unroll
    for (int i = 0; i < 4; ++i) {
      int row = rs + 32 * i;
      As[row * 8 + (cs ^ (row & 7))] = *(const bf16x8*)(A  + (size_t)(m0 + row) * lda + kaw);
      Bs[row * 8 + (cs ^ (row & 7))] = *(const bf16x8*)(BT + (size_t)(n0 + row) * ldb + ka);
    }
    __syncthreads();
#pragma unroll
    for (int kk = 0; kk < 2; ++kk) {
      bf16x8 af[4], bfr[4];
#pragma unroll
      for (int mi = 0; mi < 4; ++mi) {
        int row = wr * 64 + mi * 16 + c;
        af[mi] = As[row * 8 + ((kk * 4 + g) ^ (row & 7))];
      }
#pragma unroll
      for (int ni = 0; ni < 4; ++ni) {
        int row = wc * 64 + ni * 16 + c;
        bfr[ni] = Bs[row * 8 + ((kk * 4 + g) ^ (row & 7))];
      }
#pragma unroll
      for (int mi = 0; mi < 4; ++mi)
#pragma unroll
        for (int ni = 0; ni < 4; ++ni)
          acc[mi][ni] = __builtin_amdgcn_mfma_f32_16x16x32_bf16(af[mi], bfr[ni], acc[mi][ni], 0, 0, 0);
    }
  }
  // C frag layout: col = lane&15, row = (lane>>4)*4 + r   [m89-verified]
#pragma unroll
  for (int mi = 0; mi < 4; ++mi) {
#pragma unroll
    for (int ni = 0; ni < 4; ++ni) {
      int row = m0 + wr * 64 + mi * 16 + g * 4;
      int col = n0 + wc * 64 + ni * 16 + c;
#pragma unroll
      for (int r = 0; r < 4; ++r) {
        if constexpr (OUT_BF16)
          ((__bf16*)Cout)[(size_t)(row + r) * N + col] = (__bf16)acc[mi][ni][r];
        else
          ((float*)Cout)[(size_t)(row + r) * N + col] = acc[mi][ni][r];
      }
    }
  }
}

// -------- RoPE + RMSNorm (q,k) + quant-dequant (k,v), v stored transposed --------
// grid (T, 6), block 256 = 4 waves; wave handles one (t, head-slot).
// slots 0..15 = q heads (from bf16 qproj); 16..19 = k; 20..23 = v (from f32 kvproj).
__global__ __launch_bounds__(256) void rope_norm_quant_kernel(const __bf16* __restrict__ qproj,
                                                              const float* __restrict__ kvproj,
                                                              const float* __restrict__ cosp,
                                                              const float* __restrict__ sinp,
                                                              __bf16* __restrict__ qb,
                                                              __bf16* __restrict__ kb,
                                                              __bf16* __restrict__ vt) {
  const int t = blockIdx.x;
  const int w = threadIdx.x >> 6, lane = threadIdx.x & 63;
  const int slot = blockIdx.y * 4 + w;
  float a, b;
  if (slot < 16) {
    const __bf16* base = qproj + (size_t)t * 2048 + slot * 128;
    a = (float)base[lane]; b = (float)base[lane + 64];
  } else {
    const float* base = kvproj + (size_t)t * 1024 + (slot - 16) * 128;
    a = base[lane]; b = base[lane + 64];
  }
  float o1, o2;
  if (slot < 20) {  // rope + rmsnorm for q and k
    float cv = cosp[t * 64 + lane], sv = sinp[t * 64 + lane];
    o1 = a * cv + b * sv;
    o2 = -a * sv + b * cv;
    float ss = wave_sum64(o1 * o1 + o2 * o2);
    float sc = rsqrtf(ss * (1.0f / 128.0f) + 1.1920929e-7f);
    o1 *= sc; o2 *= sc;
  } else { o1 = a; o2 = b; }
  if (slot < 16) {
    __bf16* dst = qb + ((size_t)slot * T_SEQ + t) * HD;
    dst[lane] = (__bf16)o1; dst[lane + 64] = (__bf16)o2;
  } else {
    float amax = wave_max64(fmaxf(fabsf(o1), fabsf(o2)));
    float s = fmaxf(amax * (1.0f / 3.0f), 1e-8f);
    float d1 = fminf(fmaxf(rintf(o1 / s), -3.0f), 3.0f) * s;
    float d2 = fminf(fmaxf(rintf(o2 / s), -3.0f), 3.0f) * s;
    if (slot < 20) {
      __bf16* dst = kb + ((size_t)(slot - 16) * T_SEQ + t) * HD;
      dst[lane] = (__bf16)d1; dst[lane + 64] = (__bf16)d2;
    } else {
      __bf16* dst = vt + (size_t)(slot - 20) * HD * T_SEQ;   // [hkv][d][t]
      dst[(size_t)lane * T_SEQ + t]        = (__bf16)d1;
      dst[(size_t)(lane + 64) * T_SEQ + t] = (__bf16)d2;
    }
  }
}

// ---------------- flash sliding-window attention ----------------
__global__ __launch_bounds__(256) void attn_kernel(const __bf16* __restrict__ qb,
                                                   const __bf16* __restrict__ kb,
                                                   const __bf16* __restrict__ vt,
                                                   __bf16* __restrict__ attn) {
  __shared__ __align__(16) __bf16 plds[4][32][40];  // per-wave P tile, pad-40 rows
  const int w = threadIdx.x >> 6, lane = threadIdx.x & 63;
  const int g = lane >> 4, c = lane & 15;
  const int wg = blockIdx.x * 4 + w;
  const int h = wg >> 7, qt = wg & 127;
  const int q0 = qt * 32;
  const int hkv = h >> 2;
  const __bf16* kbase = kb + (size_t)hkv * T_SEQ * HD;
  const __bf16* vbase = vt + (size_t)hkv * HD * T_SEQ;
  const float scl = 0.08838834764831845f;  // 1/sqrt(128)

  bf16x8 qf[2][4];
#pragma unroll
  for (int mi = 0; mi < 2; ++mi)
#pragma unroll
    for (int kc = 0; kc < 4; ++kc)
      qf[mi][kc] = *(const bf16x8*)(qb + ((size_t)h * T_SEQ + q0 + 16 * mi + c) * HD + kc * 32 + 8 * g);

  f32x4 acc[2][8] = {};
  float m_[2][4], l_[2][4];
#pragma unroll
  for (int mi = 0; mi < 2; ++mi)
#pragma unroll
    for (int r = 0; r < 4; ++r) { m_[mi][r] = -1e30f; l_[mi][r] = 0.0f; }

  int lo = q0 - (WIN - 1);
  if (lo < 0) lo = 0;
  lo &= ~31;
  for (int kj0 = lo; kj0 <= q0 + 31; kj0 += 32) {
    f32x4 s[2][2] = {};
#pragma unroll
    for (int kc = 0; kc < 4; ++kc) {
      bf16x8 bk0 = *(const bf16x8*)(kbase + (size_t)(kj0 + c) * HD + kc * 32 + 8 * g);
      bf16x8 bk1 = *(const bf16x8*)(kbase + (size_t)(kj0 + 16 + c) * HD + kc * 32 + 8 * g);
#pragma unroll
      for (int mi = 0; mi < 2; ++mi) {
        s[mi][0] = __builtin_amdgcn_mfma_f32_16x16x32_bf16(qf[mi][kc], bk0, s[mi][0], 0, 0, 0);
        s[mi][1] = __builtin_amdgcn_mfma_f32_16x16x32_bf16(qf[mi][kc], bk1, s[mi][1], 0, 0, 0);
      }
    }
    float p[2][2][4];
#pragma unroll
    for (int mi = 0; mi < 2; ++mi)
#pragma unroll
      for (int ni = 0; ni < 2; ++ni)
#pragma unroll
        for (int r = 0; r < 4; ++r) {
          int qrow = q0 + 16 * mi + 4 * g + r;
          int kcol = kj0 + 16 * ni + c;
          int d = qrow - kcol;
          p[mi][ni][r] = (d >= 0 && d < WIN) ? s[mi][ni][r] * scl : -__builtin_inff();
        }
#pragma unroll
    for (int mi = 0; mi < 2; ++mi) {
      float mx[4], al[4];
#pragma unroll
      for (int r = 0; r < 4; ++r) mx[r] = fmaxf(p[mi][0][r], p[mi][1][r]);
#pragma unroll
      for (int off = 1; off < 16; off <<= 1)
#pragma unroll
        for (int r = 0; r < 4; ++r) mx[r] = fmaxf(mx[r], __shfl_xor(mx[r], off, 64));
#pragma unroll
      for (int r = 0; r < 4; ++r) {
        float mn = fmaxf(m_[mi][r], mx[r]);
        al[r] = __expf(m_[mi][r] - mn);
        m_[mi][r] = mn;
      }
#pragma unroll
      for (int ni = 0; ni < 2; ++ni)
#pragma unroll
        for (int r = 0; r < 4; ++r) p[mi][ni][r] = __expf(p[mi][ni][r] - m_[mi][r]);
      float sm[4];
#pragma unroll
      for (int r = 0; r < 4; ++r) sm[r] = p[mi][0][r] + p[mi][1][r];
#pragma unroll
      for (int off = 1; off < 16; off <<= 1)
#pragma unroll
        for (int r = 0; r < 4; ++r) sm[r] += __shfl_xor(sm[r], off, 64);
      f32x4 alv;
#pragma unroll
      for (int r = 0; r < 4; ++r) { l_[mi][r] = l_[mi][r] * al[r] + sm[r]; alv[r] = al[r]; }
#pragma unroll
      for (int df = 0; df < 8; ++df) acc[mi][df] *= alv;
    }
#pragma unroll
    for (int mi = 0; mi < 2; ++mi)
#pragma unroll
      for (int ni = 0; ni < 2; ++ni)
#pragma unroll
        for (int r = 0; r < 4; ++r)
          plds[w][16 * mi + 4 * g + r][16 * ni + c] = (__bf16)p[mi][ni][r];
    asm volatile("s_waitcnt lgkmcnt(0)" ::: "memory");
    __builtin_amdgcn_sched_barrier(0);
    bf16x8 pa[2];
#pragma unroll
    for (int mi = 0; mi < 2; ++mi) pa[mi] = *(const bf16x8*)&plds[w][16 * mi + c][8 * g];
#pragma unroll
    for (int df = 0; df < 8; ++df) {
      bf16x8 bv = *(const bf16x8*)(vbase + (size_t)(df * 16 + c) * T_SEQ + kj0 + 8 * g);
#pragma unroll
      for (int mi = 0; mi < 2; ++mi)
        acc[mi][df] = __builtin_amdgcn_mfma_f32_16x16x32_bf16(pa[mi], bv, acc[mi][df], 0, 0, 0);
    }
    asm volatile("" ::: "memory");  // keep next iter's plds writes after these reads
  }
#pragma unroll
  for (int mi = 0; mi < 2; ++mi) {
    float inv[4];
#pragma unroll
    for (int r = 0; r < 4; ++r) inv[r] = 1.0f / l_[mi][r];
#pragma unroll
    for (int df = 0; df < 8; ++df)
#pragma unroll
      for (int r = 0; r < 4; ++r) {
        float v = acc[mi][df][r] * inv[r];
        attn[(size_t)(q0 + 16 * mi + 4 * g + r) * NEMB + h * HD + df * 16 + c] = (__bf16)v;
      }
  }
}

extern "C" void kernel_launch(void* const* d_in, const int* in_sizes, int n_in,
                              void* d_out, int out_size, void* d_ws, size_t ws_size,
                              hipStream_t stream) {
  (void)in_sizes; (void)n_in; (void)out_size; (void)ws_size;
  const float* x    = (const float*)d_in[0];
  const float* cosp = (const float*)d_in[1];
  const float* sinp = (const float*)d_in[2];
  const float* Wq   = (const float*)d_in[3];
  const float* Wk   = (const float*)d_in[4];
  const float* Wv   = (const float*)d_in[5];
  const float* Wo   = (const float*)d_in[6];

  // workspace layout (bytes); total = 121,634,816
  char* ws = (char*)d_ws;
  __bf16* xsplit = (__bf16*)(ws + 0);            // [4096][4096] = [x_hi | x_lo], 33.5 MB
  __bf16* qproj  = (__bf16*)(ws + 33554432);     // [4096][2048] bf16, 16.8 MB
  float*  kvproj = (float*)(ws + 50331648);      // [4096][1024] f32, 16.8 MB
  __bf16* wqT    = (__bf16*)(ws + 67108864);     // [2048][2048], 8.4 MB
  __bf16* wkvT   = (__bf16*)(ws + 75497472);     // [1024][6144] = [hi|hi|lo], 12.6 MB
  __bf16* wot    = (__bf16*)(ws + 88080384);     // [2048][2048], 8.4 MB
  __bf16* qbuf   = (__bf16*)(ws + 96468992);     // [16][4096][128], 16.8 MB
  __bf16* kbuf   = (__bf16*)(ws + 113246208);    // [4][4096][128], 4.2 MB
  __bf16* vbuf   = (__bf16*)(ws + 117440512);    // [4][128][4096], 4.2 MB
  __bf16* abuf   = (__bf16*)(ws + 0);            // reuses xsplit (dead after proj GEMMs)

  cast_x_split_kernel<<<4096, 256, 0, stream>>>(x, xsplit);
  transpose_cast_kernel<<<dim3(256, 32), 64, 0, stream>>>(Wq, wqT, 2048, 2048);
  transpose_split_kernel<<<dim3(256, 8), 64, 0, stream>>>(Wk, wkvT, 512);
  transpose_split_kernel<<<dim3(256, 8), 64, 0, stream>>>(Wv, wkvT + (size_t)512 * 6144, 512);
  transpose_cast_kernel<<<dim3(256, 32), 64, 0, stream>>>(Wo, wot, 2048, 2048);

  // q projection: plain bf16 (q is not quantized; 0.2% error is harmless)
  gemm_kernel<true><<<dim3(16, 32), 256, 0, stream>>>(xsplit, wqT, qproj,
                                                      4096, 2048, 2048, 4096, 2048, 1 << 30);
  // k,v projection: 3-term split-bf16 (hi*hi + lo*hi + hi*lo), K=6144, A wraps at 4096.
  // Pre-quant error ~1e-5 => quant-code flips vs f32 ref become rare & random-position.
  gemm_kernel<false><<<dim3(8, 32), 256, 0, stream>>>(xsplit, wkvT, kvproj,
                                                      4096, 1024, 6144, 4096, 6144, 4096);
  rope_norm_quant_kernel<<<dim3(4096, 6), 256, 0, stream>>>(qproj, kvproj, cosp, sinp,
                                                            qbuf, kbuf, vbuf);
  attn_kernel<<<512, 256, 0, stream>>>(qbuf, kbuf, vbuf, abuf);
  // d_out is float32 (reference output dtype)
  gemm_kernel<false><<<dim3(16, 32), 256, 0, stream>>>(abuf, wot, d_out,
                                                       4096, 2048, 2048, 2048, 2048, 1 << 30);
}

// Round 4
// 517.017 us; speedup vs baseline: 1.0105x; 1.0105x over previous
//
#include <hip/hip_runtime.h>
#include <hip/hip_bf16.h>
#include <math.h>

// Problem constants
#define T_SEQ 4096
#define NEMB  2048
#define NH    16
#define NKV   4
#define HD    128
#define WIN   1024

typedef __attribute__((ext_vector_type(8))) __bf16 bf16x8;
typedef __attribute__((ext_vector_type(4))) float  f32x4;

__device__ __forceinline__ float wave_sum64(float v) {
#pragma unroll
  for (int off = 1; off < 64; off <<= 1) v += __shfl_xor(v, off, 64);
  return v;
}
__device__ __forceinline__ float wave_max64(float v) {
#pragma unroll
  for (int off = 1; off < 64; off <<= 1) v = fmaxf(v, __shfl_xor(v, off, 64));
  return v;
}

// ---- cast+split x: xsplit[4096][4096] = [x_hi | x_lo], 8 elems/thread ----
__global__ __launch_bounds__(256) void cast_x_split_kernel(const float* __restrict__ src,
                                                           __bf16* __restrict__ dst) {
  int i = blockIdx.x * 256 + threadIdx.x;   // 1M groups of 8
  int row = i >> 8, colg = i & 255;         // 256 groups per 2048-col row
  const f32x4* s4 = (const f32x4*)src;
  f32x4 a = s4[2 * i], b = s4[2 * i + 1];
  bf16x8 hi, lo;
#pragma unroll
  for (int j = 0; j < 4; ++j) {
    hi[j] = (__bf16)a[j]; lo[j] = (__bf16)(a[j] - (float)hi[j]);
    hi[j + 4] = (__bf16)b[j]; lo[j + 4] = (__bf16)(b[j] - (float)hi[j + 4]);
  }
  *(bf16x8*)(dst + (size_t)row * 4096 + colg * 8) = hi;
  *(bf16x8*)(dst + (size_t)row * 4096 + 2048 + colg * 8) = lo;
}

// ------- transpose-cast: src f32 [K=2048][N] -> dst bf16 [N][2048] ------------
__global__ __launch_bounds__(64) void transpose_cast_kernel(const float* __restrict__ src,
                                                            __bf16* __restrict__ dst,
                                                            int K, int N) {
  int kc = blockIdx.x * 8;
  int n  = blockIdx.y * 64 + threadIdx.x;
  bf16x8 o;
#pragma unroll
  for (int j = 0; j < 8; ++j) o[j] = (__bf16)src[(size_t)(kc + j) * N + n];
  *(bf16x8*)(dst + (size_t)n * K + kc) = o;
}

// ---- transpose-split-cast: src f32 [2048][N] -> dst[n][0:2048]=hi,
// ---- dst[n][2048:4096]=hi, dst[n][4096:6144]=lo  (row stride ld=6144) ----
__global__ __launch_bounds__(64) void transpose_split_kernel(const float* __restrict__ src,
                                                             __bf16* __restrict__ dst,
                                                             int N) {
  int kc = blockIdx.x * 8;
  int n  = blockIdx.y * 64 + threadIdx.x;
  bf16x8 hi, lo;
#pragma unroll
  for (int j = 0; j < 8; ++j) {
    float v = src[(size_t)(kc + j) * N + n];
    hi[j] = (__bf16)v; lo[j] = (__bf16)(v - (float)hi[j]);
  }
  *(bf16x8*)(dst + (size_t)n * 6144 + kc) = hi;
  *(bf16x8*)(dst + (size_t)n * 6144 + 2048 + kc) = hi;
  *(bf16x8*)(dst + (size_t)n * 6144 + 4096 + kc) = lo;
}

// ---------------- bf16 MFMA GEMM: C[M,N] = A[M,K] * BT[N,K]^T ----------------
// 128x128 tile, BK=64, 4 waves (2x2), 4x4 16x16 frags/wave, XOR-swizzled LDS.
template <bool OUT_BF16>
__global__ __launch_bounds__(256) void gemm_kernel(const __bf16* __restrict__ A,
                                                   const __bf16* __restrict__ BT,
                                                   void* __restrict__ Cout,
                                                   int M, int N, int K,
                                                   int lda, int ldb, int awrap) {
  __shared__ bf16x8 As[1024];  // [row 0..127][cg 0..7], slot = row*8 + (cg ^ (row&7))
  __shared__ bf16x8 Bs[1024];
  const int tid = threadIdx.x;
  const int lane = tid & 63, w = tid >> 6;
  const int wr = w >> 1, wc = w & 1;
  const int g = lane >> 4, c = lane & 15;
  const int m0 = blockIdx.y * 128, n0 = blockIdx.x * 128;
  const int rs = tid >> 3, cs = tid & 7;
  f32x4 acc[4][4] = {};
  for (int k0 = 0; k0 < K; k0 += 64) {
    int ka = k0 + cs * 8;
    int kaw = (ka >= awrap) ? ka - awrap : ka;
    __syncthreads();
#pragma unroll
    for (int i = 0; i < 4; ++i) {
      int row = rs + 32 * i;
      As[row * 8 + (cs ^ (row & 7))] = *(const bf16x8*)(A  + (size_t)(m0 + row) * lda + kaw);
      Bs[row * 8 + (cs ^ (row & 7))] = *(const bf16x8*)(BT + (size_t)(n0 + row) * ldb + ka);
    }
    __syncthreads();
#pragma unroll
    for (int kk = 0; kk < 2; ++kk) {
      bf16x8 af[4], bfr[4];
#pragma unroll
      for (int mi = 0; mi < 4; ++mi) {
        int row = wr * 64 + mi * 16 + c;
        af[mi] = As[row * 8 + ((kk * 4 + g) ^ (row & 7))];
      }
#pragma unroll
      for (int ni = 0; ni < 4; ++ni) {
        int row = wc * 64 + ni * 16 + c;
        bfr[ni] = Bs[row * 8 + ((kk * 4 + g) ^ (row & 7))];
      }
#pragma unroll
      for (int mi = 0; mi < 4; ++mi)
#pragma unroll
        for (int ni = 0; ni < 4; ++ni)
          acc[mi][ni] = __builtin_amdgcn_mfma_f32_16x16x32_bf16(af[mi], bfr[ni], acc[mi][ni], 0, 0, 0);
    }
  }
  // C frag layout: col = lane&15, row = (lane>>4)*4 + r   [m89-verified]
#pragma unroll
  for (int mi = 0; mi < 4; ++mi) {
#pragma unroll
    for (int ni = 0; ni < 4; ++ni) {
      int row = m0 + wr * 64 + mi * 16 + g * 4;
      int col = n0 + wc * 64 + ni * 16 + c;
#pragma unroll
      for (int r = 0; r < 4; ++r) {
        if constexpr (OUT_BF16)
          ((__bf16*)Cout)[(size_t)(row + r) * N + col] = (__bf16)acc[mi][ni][r];
        else
          ((float*)Cout)[(size_t)(row + r) * N + col] = acc[mi][ni][r];
      }
    }
  }
}

// -------- RoPE + RMSNorm (q,k) + quant-dequant (k,v), v stored transposed --------
__global__ __launch_bounds__(256) void rope_norm_quant_kernel(const __bf16* __restrict__ qproj,
                                                              const float* __restrict__ kvproj,
                                                              const float* __restrict__ cosp,
                                                              const float* __restrict__ sinp,
                                                              __bf16* __restrict__ qb,
                                                              __bf16* __restrict__ kb,
                                                              __bf16* __restrict__ vt) {
  const int t = blockIdx.x;
  const int w = threadIdx.x >> 6, lane = threadIdx.x & 63;
  const int slot = blockIdx.y * 4 + w;
  float a, b;
  if (slot < 16) {
    const __bf16* base = qproj + (size_t)t * 2048 + slot * 128;
    a = (float)base[lane]; b = (float)base[lane + 64];
  } else {
    const float* base = kvproj + (size_t)t * 1024 + (slot - 16) * 128;
    a = base[lane]; b = base[lane + 64];
  }
  float o1, o2;
  if (slot < 20) {  // rope + rmsnorm for q and k
    float cv = cosp[t * 64 + lane], sv = sinp[t * 64 + lane];
    o1 = a * cv + b * sv;
    o2 = -a * sv + b * cv;
    float ss = wave_sum64(o1 * o1 + o2 * o2);
    float sc = rsqrtf(ss * (1.0f / 128.0f) + 1.1920929e-7f);
    o1 *= sc; o2 *= sc;
  } else { o1 = a; o2 = b; }
  if (slot < 16) {
    __bf16* dst = qb + ((size_t)slot * T_SEQ + t) * HD;
    dst[lane] = (__bf16)o1; dst[lane + 64] = (__bf16)o2;
  } else {
    float amax = wave_max64(fmaxf(fabsf(o1), fabsf(o2)));
    float s = fmaxf(amax * (1.0f / 3.0f), 1e-8f);
    float d1 = fminf(fmaxf(rintf(o1 / s), -3.0f), 3.0f) * s;
    float d2 = fminf(fmaxf(rintf(o2 / s), -3.0f), 3.0f) * s;
    if (slot < 20) {
      __bf16* dst = kb + ((size_t)(slot - 16) * T_SEQ + t) * HD;
      dst[lane] = (__bf16)d1; dst[lane + 64] = (__bf16)d2;
    } else {
      __bf16* dst = vt + (size_t)(slot - 20) * HD * T_SEQ;   // [hkv][d][t]
      dst[(size_t)lane * T_SEQ + t]        = (__bf16)d1;
      dst[(size_t)(lane + 64) * T_SEQ + t] = (__bf16)d2;
    }
  }
}

// ---------------- flash sliding-window attention, no-max-tracking ----------------
// RMSNorm bounds |score*scl| <= ~12.5, so exp() without max subtraction is exact
// (softmax is shift-invariant) and overflow-free: sum <= 1056*e^12.5 ~ 2.8e8 (f32 ok).
// Removes per-step shuffle reduces + acc rescale; row-sum kept per-lane, reduced once.
__global__ __launch_bounds__(256) void attn_kernel(const __bf16* __restrict__ qb,
                                                   const __bf16* __restrict__ kb,
                                                   const __bf16* __restrict__ vt,
                                                   __bf16* __restrict__ attn) {
  __shared__ __align__(16) __bf16 plds[4][32][40];  // per-wave P tile, pad-40 rows
  const int w = threadIdx.x >> 6, lane = threadIdx.x & 63;
  const int g = lane >> 4, c = lane & 15;
  const int wg = blockIdx.x * 4 + w;
  const int h = wg >> 7, qt = wg & 127;
  const int q0 = qt * 32;
  const int hkv = h >> 2;
  const __bf16* kbase = kb + (size_t)hkv * T_SEQ * HD;
  const __bf16* vbase = vt + (size_t)hkv * HD * T_SEQ;
  const float scl = 0.08838834764831845f;  // 1/sqrt(128)

  bf16x8 qf[2][4];
#pragma unroll
  for (int mi = 0; mi < 2; ++mi)
#pragma unroll
    for (int kc = 0; kc < 4; ++kc)
      qf[mi][kc] = *(const bf16x8*)(qb + ((size_t)h * T_SEQ + q0 + 16 * mi + c) * HD + kc * 32 + 8 * g);

  f32x4 acc[2][8] = {};
  float lsum[2][4] = {};

  int lo = q0 - (WIN - 1);
  if (lo < 0) lo = 0;
  lo &= ~31;
  for (int kj0 = lo; kj0 <= q0 + 31; kj0 += 32) {
    f32x4 s[2][2] = {};
#pragma unroll
    for (int kc = 0; kc < 4; ++kc) {
      bf16x8 bk0 = *(const bf16x8*)(kbase + (size_t)(kj0 + c) * HD + kc * 32 + 8 * g);
      bf16x8 bk1 = *(const bf16x8*)(kbase + (size_t)(kj0 + 16 + c) * HD + kc * 32 + 8 * g);
#pragma unroll
      for (int mi = 0; mi < 2; ++mi) {
        s[mi][0] = __builtin_amdgcn_mfma_f32_16x16x32_bf16(qf[mi][kc], bk0, s[mi][0], 0, 0, 0);
        s[mi][1] = __builtin_amdgcn_mfma_f32_16x16x32_bf16(qf[mi][kc], bk1, s[mi][1], 0, 0, 0);
      }
    }
    // p = valid ? exp(s*scl) : 0 ; accumulate per-lane row-sums (no cross-lane ops)
    float p[2][2][4];
#pragma unroll
    for (int mi = 0; mi < 2; ++mi)
#pragma unroll
      for (int ni = 0; ni < 2; ++ni)
#pragma unroll
        for (int r = 0; r < 4; ++r) {
          int qrow = q0 + 16 * mi + 4 * g + r;
          int kcol = kj0 + 16 * ni + c;
          int d = qrow - kcol;
          float e = __expf(s[mi][ni][r] * scl);
          p[mi][ni][r] = (d >= 0 && d < WIN) ? e : 0.0f;
        }
#pragma unroll
    for (int mi = 0; mi < 2; ++mi)
#pragma unroll
      for (int r = 0; r < 4; ++r)
        lsum[mi][r] += p[mi][0][r] + p[mi][1][r];
    // P (C-frag layout) -> LDS -> PV A-frag layout
#pragma unroll
    for (int mi = 0; mi < 2; ++mi)
#pragma unroll
      for (int ni = 0; ni < 2; ++ni)
#pragma unroll
        for (int r = 0; r < 4; ++r)
          plds[w][16 * mi + 4 * g + r][16 * ni + c] = (__bf16)p[mi][ni][r];
    asm volatile("s_waitcnt lgkmcnt(0)" ::: "memory");
    __builtin_amdgcn_sched_barrier(0);
    bf16x8 pa[2];
#pragma unroll
    for (int mi = 0; mi < 2; ++mi) pa[mi] = *(const bf16x8*)&plds[w][16 * mi + c][8 * g];
#pragma unroll
    for (int df = 0; df < 8; ++df) {
      bf16x8 bv = *(const bf16x8*)(vbase + (size_t)(df * 16 + c) * T_SEQ + kj0 + 8 * g);
#pragma unroll
      for (int mi = 0; mi < 2; ++mi)
        acc[mi][df] = __builtin_amdgcn_mfma_f32_16x16x32_bf16(pa[mi], bv, acc[mi][df], 0, 0, 0);
    }
    asm volatile("" ::: "memory");  // keep next iter's plds writes after these reads
  }
  // one deferred 16-lane row-sum reduce, then normalize + store
#pragma unroll
  for (int mi = 0; mi < 2; ++mi) {
#pragma unroll
    for (int off = 1; off < 16; off <<= 1)
#pragma unroll
      for (int r = 0; r < 4; ++r) lsum[mi][r] += __shfl_xor(lsum[mi][r], off, 64);
    float inv[4];
#pragma unroll
    for (int r = 0; r < 4; ++r) inv[r] = 1.0f / lsum[mi][r];
#pragma unroll
    for (int df = 0; df < 8; ++df)
#pragma unroll
      for (int r = 0; r < 4; ++r) {
        float v = acc[mi][df][r] * inv[r];
        attn[(size_t)(q0 + 16 * mi + 4 * g + r) * NEMB + h * HD + df * 16 + c] = (__bf16)v;
      }
  }
}

extern "C" void kernel_launch(void* const* d_in, const int* in_sizes, int n_in,
                              void* d_out, int out_size, void* d_ws, size_t ws_size,
                              hipStream_t stream) {
  (void)in_sizes; (void)n_in; (void)out_size; (void)ws_size;
  const float* x    = (const float*)d_in[0];
  const float* cosp = (const float*)d_in[1];
  const float* sinp = (const float*)d_in[2];
  const float* Wq   = (const float*)d_in[3];
  const float* Wk   = (const float*)d_in[4];
  const float* Wv   = (const float*)d_in[5];
  const float* Wo   = (const float*)d_in[6];

  // workspace layout (bytes); total = 121,634,816
  char* ws = (char*)d_ws;
  __bf16* xsplit = (__bf16*)(ws + 0);            // [4096][4096] = [x_hi | x_lo], 33.5 MB
  __bf16* qproj  = (__bf16*)(ws + 33554432);     // [4096][2048] bf16, 16.8 MB
  float*  kvproj = (float*)(ws + 50331648);      // [4096][1024] f32, 16.8 MB
  __bf16* wqT    = (__bf16*)(ws + 67108864);     // [2048][2048], 8.4 MB
  __bf16* wkvT   = (__bf16*)(ws + 75497472);     // [1024][6144] = [hi|hi|lo], 12.6 MB
  __bf16* wot    = (__bf16*)(ws + 88080384);     // [2048][2048], 8.4 MB
  __bf16* qbuf   = (__bf16*)(ws + 96468992);     // [16][4096][128], 16.8 MB
  __bf16* kbuf   = (__bf16*)(ws + 113246208);    // [4][4096][128], 4.2 MB
  __bf16* vbuf   = (__bf16*)(ws + 117440512);    // [4][128][4096], 4.2 MB
  __bf16* abuf   = (__bf16*)(ws + 0);            // reuses xsplit (dead after proj GEMMs)

  cast_x_split_kernel<<<4096, 256, 0, stream>>>(x, xsplit);
  transpose_cast_kernel<<<dim3(256, 32), 64, 0, stream>>>(Wq, wqT, 2048, 2048);
  transpose_split_kernel<<<dim3(256, 8), 64, 0, stream>>>(Wk, wkvT, 512);
  transpose_split_kernel<<<dim3(256, 8), 64, 0, stream>>>(Wv, wkvT + (size_t)512 * 6144, 512);
  transpose_cast_kernel<<<dim3(256, 32), 64, 0, stream>>>(Wo, wot, 2048, 2048);

  // q projection: plain bf16 (q is not quantized; 0.2% error is harmless)
  gemm_kernel<true><<<dim3(16, 32), 256, 0, stream>>>(xsplit, wqT, qproj,
                                                      4096, 2048, 2048, 4096, 2048, 1 << 30);
  // k,v projection: 3-term split-bf16 (hi*hi + lo*hi + hi*lo), K=6144, A wraps at 4096.
  gemm_kernel<false><<<dim3(8, 32), 256, 0, stream>>>(xsplit, wkvT, kvproj,
                                                      4096, 1024, 6144, 4096, 6144, 4096);
  rope_norm_quant_kernel<<<dim3(4096, 6), 256, 0, stream>>>(qproj, kvproj, cosp, sinp,
                                                            qbuf, kbuf, vbuf);
  attn_kernel<<<512, 256, 0, stream>>>(qbuf, kbuf, vbuf, abuf);
  // d_out is float32 (reference output dtype)
  gemm_kernel<false><<<dim3(16, 32), 256, 0, stream>>>(abuf, wot, d_out,
                                                       4096, 2048, 2048, 2048, 2048, 1 << 30);
}